// Round 8
// baseline (125.562 us; speedup 1.0000x reference)
//
#include <hip/hip_runtime.h>

#define EPS_F 1e-6f
#define LOG2E 1.4426950408889634f

typedef float f4a __attribute__((ext_vector_type(4), aligned(16)));

// d_ws layout: pws[64 groups][16 slices][1920 floats] | cb[16] | cnt[64]
#define PWS_FLOATS (64 * 16 * 1920)

// Kernel 0: precompute coefficients + zero the group counters (d_ws is
// re-poisoned 0xAA before every timed call). cb[kc] = -0.5*log2e/std^2,
// cb[15] = fast-path flag (all K coefs identical per channel).
__global__ void icgp_coef_kernel(const float* __restrict__ log_std,
                                 float* __restrict__ cb,
                                 unsigned int* __restrict__ cnt) {
    if (threadIdx.x < 64) cnt[threadIdx.x] = 0u;
    if (threadIdx.x == 0) {
        float c[15];
        #pragma unroll
        for (int kc = 0; kc < 15; ++kc) {
            const float s = __expf(log_std[kc]) + EPS_F;
            c[kc] = -0.5f * LOG2E / (s * s);
        }
        bool uni = true;
        #pragma unroll
        for (int k = 1; k < 5; ++k)
            #pragma unroll
            for (int ch = 0; ch < 3; ++ch)
                uni = uni && (c[k * 3 + ch] == c[ch]);
        #pragma unroll
        for (int kc = 0; kc < 15; ++kc) cb[kc] = c[kc];
        cb[15] = uni ? 1.0f : 0.0f;
    }
}

// Main kernel: grid = 1024 = B(8) x m-groups(8, 128 m) x n-chunks(16, 64 n);
// block = 4 waves -> 4 blocks/CU (measured sweet spot). Each lane owns TWO m's
// (lane, lane+64 of the group's 128) so one wave-uniform n-row serves 128 m's.
// Per-n feat/xa are wave-uniform loads (readfirstlane'd row base, const
// __restrict -> scalar/broadcast path, no staging, no inner-loop LDS).
// Epilogue: 4-wave LDS combine -> plain coalesced slice store to d_ws ->
// release fence + device-scope counter; the 16th arriver of each (b,mg)
// group reduces its 16 slices and writes out. No k2 launch, no spinning.
__global__ __launch_bounds__(256, 4) void icgp_partial_kernel(
    const float* __restrict__ xa,       // (B, 1024, 1, 3)
    const float* __restrict__ feat,     // (B, 1024, 5, 3)
    const float* __restrict__ xt,       // (B, 1024, 1, 3)
    const float* __restrict__ cb,       // 15 coefs + flag
    float* __restrict__ pws,            // partial slices
    unsigned int* __restrict__ cnt,     // 64 group counters
    float* __restrict__ out)            // (B, 1024, 5, 3)
{
    __shared__ float lds[7680];         // 4 x 1920 combine buffer (30 KB)

    const int bid  = blockIdx.x;
    const int nc   = bid & 15;          // n-chunk (64 n's)
    const int mg   = (bid >> 4) & 7;    // m-group (128 m's)
    const int b    = bid >> 7;
    const int g    = b * 8 + mg;        // group id 0..63
    const int tid  = threadIdx.x;
    const int wv   = tid >> 6;          // 0..3
    const int lane = tid & 63;

    // Uniform coefficient load (SGPR-resident).
    float coef[15];
    #pragma unroll
    for (int kc = 0; kc < 15; ++kc) coef[kc] = cb[kc];
    const bool uni = (cb[15] != 0.0f);

    // Two target points per lane.
    const int m0 = mg * 128 + lane;
    const int m1 = m0 + 64;
    const float t00 = xt[(b * 1024 + m0) * 3 + 0];
    const float t01 = xt[(b * 1024 + m0) * 3 + 1];
    const float t02 = xt[(b * 1024 + m0) * 3 + 2];
    const float t10 = xt[(b * 1024 + m1) * 3 + 0];
    const float t11 = xt[(b * 1024 + m1) * 3 + 1];
    const float t12 = xt[(b * 1024 + m1) * 3 + 2];

    // Wave-uniform row base.
    const int rw = __builtin_amdgcn_readfirstlane(nc * 64 + wv * 16);
    const float* __restrict__ fg = feat + (size_t)b * 1024 * 15;
    const float* __restrict__ ag = xa   + (size_t)b * 1024 * 3;

    float acc0[15], acc1[15];
    #pragma unroll
    for (int kc = 0; kc < 15; ++kc) { acc0[kc] = 0.0f; acc1[kc] = 0.0f; }

    if (uni) {
        const float c0 = coef[0], c1 = coef[1], c2 = coef[2];
        #pragma unroll 4
        for (int i = 0; i < 16; ++i) {
            const int r = rw + i;                       // uniform
            const float* __restrict__ f = fg + r * 15;  // uniform row
            const float a0 = ag[r * 3 + 0];
            const float a1 = ag[r * 3 + 1];
            const float a2 = ag[r * 3 + 2];
            float d0, d1, d2;
            d0 = a0 - t00; d0 *= d0;
            d1 = a1 - t01; d1 *= d1;
            d2 = a2 - t02; d2 *= d2;
            const float w00 = __builtin_amdgcn_exp2f(d0 * c0);
            const float w01 = __builtin_amdgcn_exp2f(d1 * c1);
            const float w02 = __builtin_amdgcn_exp2f(d2 * c2);
            d0 = a0 - t10; d0 *= d0;
            d1 = a1 - t11; d1 *= d1;
            d2 = a2 - t12; d2 *= d2;
            const float w10 = __builtin_amdgcn_exp2f(d0 * c0);
            const float w11 = __builtin_amdgcn_exp2f(d1 * c1);
            const float w12 = __builtin_amdgcn_exp2f(d2 * c2);
            #pragma unroll
            for (int k = 0; k < 5; ++k) {
                acc0[k * 3 + 0] += w00 * f[k * 3 + 0];
                acc0[k * 3 + 1] += w01 * f[k * 3 + 1];
                acc0[k * 3 + 2] += w02 * f[k * 3 + 2];
                acc1[k * 3 + 0] += w10 * f[k * 3 + 0];
                acc1[k * 3 + 1] += w11 * f[k * 3 + 1];
                acc1[k * 3 + 2] += w12 * f[k * 3 + 2];
            }
        }
    } else {
        // General path: 15 exps per (n, m) (correct for arbitrary log_std).
        for (int i = 0; i < 16; ++i) {
            const int r = rw + i;
            const float* __restrict__ f = fg + r * 15;
            const float a0 = ag[r * 3 + 0];
            const float a1 = ag[r * 3 + 1];
            const float a2 = ag[r * 3 + 2];
            float dd0[3], dd1[3];
            dd0[0] = a0 - t00; dd0[0] *= dd0[0];
            dd0[1] = a1 - t01; dd0[1] *= dd0[1];
            dd0[2] = a2 - t02; dd0[2] *= dd0[2];
            dd1[0] = a0 - t10; dd1[0] *= dd1[0];
            dd1[1] = a1 - t11; dd1[1] *= dd1[1];
            dd1[2] = a2 - t12; dd1[2] *= dd1[2];
            #pragma unroll
            for (int k = 0; k < 5; ++k)
                #pragma unroll
                for (int c = 0; c < 3; ++c) {
                    acc0[k * 3 + c] +=
                        __builtin_amdgcn_exp2f(dd0[c] * coef[k * 3 + c]) * f[k * 3 + c];
                    acc1[k * 3 + c] +=
                        __builtin_amdgcn_exp2f(dd1[c] * coef[k * 3 + c]) * f[k * 3 + c];
                }
        }
    }

    // ---- in-block combine of 4 wave-partials ----
    #pragma unroll
    for (int kc = 0; kc < 15; ++kc) {
        lds[wv * 1920 + lane * 15 + kc]        = acc0[kc];
        lds[wv * 1920 + (64 + lane) * 15 + kc] = acc1[kc];
    }
    __syncthreads();

    float* __restrict__ pb = pws + ((size_t)g * 16 + nc) * 1920;
    #pragma unroll
    for (int j = 0; j < 8; ++j) {
        const int o = j * 256 + tid;            // 0..1919
        if (o < 1920) {
            float s = 0.0f;
            #pragma unroll
            for (int w = 0; w < 4; ++w)
                s += lds[w * 1920 + o];          // consecutive addr
            pb[o] = s;                           // coalesced
        }
    }

    // ---- tail reduce: 16th arriver of this group sums the 16 slices ----
    __syncthreads();                             // slice fully stored
    __shared__ unsigned int last;
    if (tid == 0) {
        __threadfence();                         // release our slice
        last = atomicAdd(&cnt[g], 1u);
    }
    __syncthreads();
    if (last == 15u) {
        __threadfence();                         // acquire others' slices
        const float* __restrict__ rbase = pws + (size_t)g * 16 * 1920;
        float* __restrict__ ob = out + ((size_t)b * 1024 + mg * 128) * 15;
        #pragma unroll
        for (int j = 0; j < 2; ++j) {
            const int idx = j * 256 + tid;       // f4 index, < 480
            if (idx < 480) {
                f4a s = {0.0f, 0.0f, 0.0f, 0.0f};
                #pragma unroll
                for (int sl = 0; sl < 16; ++sl) {
                    const f4a v = *(const f4a*)(rbase + sl * 1920 + idx * 4);
                    s.x += v.x; s.y += v.y; s.z += v.z; s.w += v.w;
                }
                *(f4a*)(ob + idx * 4) = s;
            }
        }
    }
}

extern "C" void kernel_launch(void* const* d_in, const int* in_sizes, int n_in,
                              void* d_out, int out_size, void* d_ws, size_t ws_size,
                              hipStream_t stream) {
    const float* xa      = (const float*)d_in[0];  // (8,1024,1,3)
    const float* feat    = (const float*)d_in[1];  // (8,1024,5,3)
    const float* xt      = (const float*)d_in[2];  // (8,1024,1,3)
    const float* log_std = (const float*)d_in[3];  // (1,5,3)
    float* out = (float*)d_out;                    // (8,1024,5,3)
    float* pws = (float*)d_ws;                     // 7.86 MB partial slices
    float* cb  = pws + PWS_FLOATS;                 // 16 floats coef block
    unsigned int* cnt = (unsigned int*)(cb + 16);  // 64 group counters

    icgp_coef_kernel<<<dim3(1), dim3(64), 0, stream>>>(log_std, cb, cnt);
    icgp_partial_kernel<<<dim3(1024), dim3(256), 0, stream>>>(
        xa, feat, xt, cb, pws, cnt, out);
}

// Round 9
// 73.715 us; speedup vs baseline: 1.7033x; 1.7033x over previous
//
#include <hip/hip_runtime.h>

#define EPS_F 1e-6f
#define LOG2E 1.4426950408889634f

typedef float f4a __attribute__((ext_vector_type(4), aligned(16)));

// Force a (known-uniform) float into an SGPR.
__device__ __forceinline__ float rfl(float x) {
    return __builtin_bit_cast(float, __builtin_amdgcn_readfirstlane(__builtin_bit_cast(int, x)));
}

// Kernel 1: partial sums over 128-wide n-chunks.  (round-4 champion structure)
// grid = 1024 blocks = B(8) x m-tiles(16) x n-chunks(8); block = 256 thr = 4 waves.
// lane <-> m (64 m's per block, same set for all 4 waves); wave w sums n in
// [chunk*128 + w*32, +32). feat/xa rows staged in LDS (rows padded to 16/4
// floats -> 16B-aligned b128 reads); inner-loop ds_reads are all-lanes-same-
// address -> HW broadcast, no per-lane VMEM. 4-wave partials combined in LDS;
// 8 n-chunk slices stored plain+coalesced to d_ws. No atomics, no fences.
// launch_bounds without min-waves: occupancy is grid-capped at 4 blocks/CU,
// so let the allocator use VGPRs for deeper load pipelining.
__global__ __launch_bounds__(256) void icgp_partial_kernel(
    const float* __restrict__ xa,       // (B, 1024, 1, 3)
    const float* __restrict__ feat,     // (B, 1024, 5, 3)
    const float* __restrict__ xt,       // (B, 1024, 1, 3)
    const float* __restrict__ log_std,  // (1, 5, 3)
    float* __restrict__ pws)            // (8, B*1024*15) partials
{
    // staging: sfeat = lds[0..2047] (128 rows x 16), sxa = lds[2048..2559]
    // (128 rows x 4); epilogue reuses lds[0..3839] (256 x 15).
    __shared__ float lds[3840];         // 15360 B

    const int bid  = blockIdx.x;
    const int nsb  = bid & 7;           // n-chunk
    const int mt   = (bid >> 3) & 15;   // m-tile (64 m's)
    const int b    = bid >> 7;
    const int tid  = threadIdx.x;
    const int wv   = tid >> 6;          // 0..3
    const int lane = tid & 63;
    const int m    = mt * 64 + lane;
    const int n0   = nsb * 128;

    // ---- stage feat (1920 floats) and xa (384 floats) into padded LDS ----
    const float* __restrict__ fg = feat + ((size_t)b * 1024 + n0) * 15; // 16B-aligned
    for (int j = tid; j < 480; j += 256) {
        const f4a v = *(const f4a*)(fg + j * 4);
        #pragma unroll
        for (int e = 0; e < 4; ++e) {
            const int g = j * 4 + e;
            const int r = g / 15, c = g - r * 15;
            lds[r * 16 + c] = v[e];
        }
    }
    const float* __restrict__ ag = xa + ((size_t)b * 1024 + n0) * 3;    // 16B-aligned
    if (tid < 96) {
        const f4a v = *(const f4a*)(ag + tid * 4);
        #pragma unroll
        for (int e = 0; e < 4; ++e) {
            const int g = tid * 4 + e;
            const int r = g / 3, c = g - r * 3;
            lds[2048 + r * 4 + c] = v[e];
        }
    }

    // ---- coefficients: wt = exp2(coef*(xa-xt)^2), coef = -0.5*log2e/std^2 ----
    float coef[15];
    #pragma unroll
    for (int kc = 0; kc < 15; ++kc) {
        const float s = __expf(log_std[kc]) + EPS_F;
        coef[kc] = rfl(-0.5f * LOG2E / (s * s));
    }
    bool uni = true;
    #pragma unroll
    for (int k = 1; k < 5; ++k)
        #pragma unroll
        for (int c = 0; c < 3; ++c)
            uni = uni && (coef[k * 3 + c] == coef[c]);

    const float t0 = xt[(b * 1024 + m) * 3 + 0];
    const float t1 = xt[(b * 1024 + m) * 3 + 1];
    const float t2 = xt[(b * 1024 + m) * 3 + 2];

    __syncthreads();

    float acc[15];
    #pragma unroll
    for (int kc = 0; kc < 15; ++kc) acc[kc] = 0.0f;

    const int rb = wv * 32;             // this wave's first LDS row

    if (uni) {
        const float c0 = coef[0], c1 = coef[1], c2 = coef[2];
        #pragma unroll 8
        for (int i = 0; i < 32; ++i) {
            const float* __restrict__ row = &lds[(rb + i) * 16];
            const f4a fA = *(const f4a*)(row);        // kc 0..3
            const f4a fB = *(const f4a*)(row + 4);    // kc 4..7
            const f4a fC = *(const f4a*)(row + 8);    // kc 8..11
            const f4a fD = *(const f4a*)(row + 12);   // kc 12..14 (+pad)
            const f4a av = *(const f4a*)(&lds[2048 + (rb + i) * 4]); // xa (+pad)
            float d0 = av.x - t0; d0 *= d0;
            float d1 = av.y - t1; d1 *= d1;
            float d2 = av.z - t2; d2 *= d2;
            const float w0 = __builtin_amdgcn_exp2f(d0 * c0);
            const float w1 = __builtin_amdgcn_exp2f(d1 * c1);
            const float w2 = __builtin_amdgcn_exp2f(d2 * c2);
            acc[0]  += w0 * fA.x;  acc[1]  += w1 * fA.y;  acc[2]  += w2 * fA.z;
            acc[3]  += w0 * fA.w;  acc[4]  += w1 * fB.x;  acc[5]  += w2 * fB.y;
            acc[6]  += w0 * fB.z;  acc[7]  += w1 * fB.w;  acc[8]  += w2 * fC.x;
            acc[9]  += w0 * fC.y;  acc[10] += w1 * fC.z;  acc[11] += w2 * fC.w;
            acc[12] += w0 * fD.x;  acc[13] += w1 * fD.y;  acc[14] += w2 * fD.z;
        }
    } else {
        // General path: 15 exps per n (correct for arbitrary log_std).
        for (int i = 0; i < 32; ++i) {
            const float* __restrict__ row = &lds[(rb + i) * 16];
            float fv[16];
            *(f4a*)(fv)      = *(const f4a*)(row);
            *(f4a*)(fv + 4)  = *(const f4a*)(row + 4);
            *(f4a*)(fv + 8)  = *(const f4a*)(row + 8);
            *(f4a*)(fv + 12) = *(const f4a*)(row + 12);
            const f4a av = *(const f4a*)(&lds[2048 + (rb + i) * 4]);
            float dd[3];
            dd[0] = av.x - t0; dd[0] *= dd[0];
            dd[1] = av.y - t1; dd[1] *= dd[1];
            dd[2] = av.z - t2; dd[2] *= dd[2];
            #pragma unroll
            for (int k = 0; k < 5; ++k)
                #pragma unroll
                for (int c = 0; c < 3; ++c)
                    acc[k * 3 + c] +=
                        __builtin_amdgcn_exp2f(dd[c] * coef[k * 3 + c]) * fv[k * 3 + c];
        }
    }

    // ---- in-block combine of the 4 wave-partials, plain store to pws ----
    __syncthreads();                    // all waves done reading staging
    #pragma unroll
    for (int kc = 0; kc < 15; ++kc) lds[tid * 15 + kc] = acc[kc];
    __syncthreads();

    float* __restrict__ pb = pws + (size_t)nsb * 122880
                                 + ((size_t)b * 1024 + mt * 64) * 15;
    #pragma unroll
    for (int j = 0; j < 4; ++j) {
        const int oidx = j * 256 + tid;         // 0..959
        if (oidx < 960) {
            const int mm = oidx / 15, kc = oidx - mm * 15;
            float s = 0.0f;
            #pragma unroll
            for (int w = 0; w < 4; ++w)
                s += lds[(w * 64 + mm) * 15 + kc];
            pb[oidx] = s;                        // coalesced
        }
    }
}

// Kernel 2: sum the 8 n-chunk slices, float4-vectorized.
// 30720 float4 outputs; grid 120 x 256: 8 f4 loads + 1 f4 store per thread.
__global__ __launch_bounds__(256) void icgp_reduce_kernel(
    const float* __restrict__ pws, float* __restrict__ out)
{
    const int idx = blockIdx.x * 256 + threadIdx.x;   // < 30720
    f4a s = {0.0f, 0.0f, 0.0f, 0.0f};
    #pragma unroll
    for (int ns = 0; ns < 8; ++ns) {
        const f4a v = *(const f4a*)(pws + (size_t)ns * 122880 + idx * 4);
        s.x += v.x; s.y += v.y; s.z += v.z; s.w += v.w;
    }
    *(f4a*)(out + idx * 4) = s;
}

extern "C" void kernel_launch(void* const* d_in, const int* in_sizes, int n_in,
                              void* d_out, int out_size, void* d_ws, size_t ws_size,
                              hipStream_t stream) {
    const float* xa      = (const float*)d_in[0];  // (8,1024,1,3)
    const float* feat    = (const float*)d_in[1];  // (8,1024,5,3)
    const float* xt      = (const float*)d_in[2];  // (8,1024,1,3)
    const float* log_std = (const float*)d_in[3];  // (1,5,3)
    float* out = (float*)d_out;                    // (8,1024,5,3)
    float* pws = (float*)d_ws;                     // 8 x 122880 floats = 3.93 MB

    icgp_partial_kernel<<<dim3(1024), dim3(256), 0, stream>>>(xa, feat, xt, log_std, pws);
    icgp_reduce_kernel<<<dim3(120), dim3(256), 0, stream>>>(pws, out);
}